// Round 3
// baseline (1037.156 us; speedup 1.0000x reference)
//
#include <hip/hip_runtime.h>
#include <math.h>

#define BB 16
#define NN 8192
#define CC 128
#define KK 128
#define LL 4

#define APX 40    // padded LDS stride for final_kernel staging
#define BPX 136   // LDS row stride for 128-wide transpose tiles

typedef short bf16x8 __attribute__((ext_vector_type(8)));
typedef float f32x4 __attribute__((ext_vector_type(4)));

typedef unsigned short u16;
typedef unsigned int u32;

__device__ __forceinline__ float gelu_f(float v){ return 0.5f*v*(1.0f + erff(v*0.70710678118f)); }

__device__ __forceinline__ u16 f2bf(float f){
  u32 u = __float_as_uint(f);
  return (u16)((u + 0x7FFFu + ((u >> 16) & 1u)) >> 16);   // RNE
}
__device__ __forceinline__ float bf2f(u16 u){ return __uint_as_float(((u32)u) << 16); }
__device__ __forceinline__ u32 pk2(float a, float b){
  return (u32)f2bf(a) | ((u32)f2bf(b) << 16);
}

// async global->LDS, 16B per lane; LDS dst is wave-uniform base + lane*16
__device__ __forceinline__ void gll16(const u16* g, u16* l){
  __builtin_amdgcn_global_load_lds(
      (const __attribute__((address_space(1))) void*)g,
      (__attribute__((address_space(3))) void*)l, 16, 0, 0);
}

// ---------------------------------------------------------------- bases
__global__ __launch_bounds__(256) void bases_kernel(
    const float* __restrict__ X, const float* __restrict__ modes,
    u16* __restrict__ bc, u16* __restrict__ bs,
    u16* __restrict__ bcT, u16* __restrict__ bsT,
    float* __restrict__ mA, float* __restrict__ sA)
{
  __shared__ float smodes[2*KK];
  __shared__ u16 shc[64*BPX];
  __shared__ u16 shs[64*BPX];
  const int b = blockIdx.x;
  const int x0 = blockIdx.y*64;
  const int t = threadIdx.x;
  smodes[t] = modes[t];
  const int xl = t & 63;
  const int kq = t >> 6;
  const int x = x0 + xl;
  const float* xp = X + ((size_t)b*NN + x)*7;
  const float g0 = xp[3], g1 = xp[4], wv = xp[5], mv = xp[6];
  if (kq == 0){
    mA[b*NN + x] = mv;
    sA[b*NN + x] = wv * (float)NN;
  }
  __syncthreads();
  #pragma unroll 4
  for (int kk = 0; kk < 32; ++kk){
    const int k = kq*32 + kk;
    const float tt = g0*smodes[2*k] + g1*smodes[2*k+1];
    float sn, cs;
    __sincosf(tt, &sn, &cs);
    shc[xl*BPX + k] = f2bf(cs*mv);
    shs[xl*BPX + k] = f2bf(sn*mv);
  }
  __syncthreads();
  for (int idx = t; idx < 64*16; idx += 256){
    const int row = idx >> 4, c16 = (idx & 15)*8;
    const size_t dst = ((size_t)b*NN + x0 + row)*KK + c16;
    *(uint4*)&bcT[dst] = *(const uint4*)&shc[row*BPX + c16];
    *(uint4*)&bsT[dst] = *(const uint4*)&shs[row*BPX + c16];
  }
  for (int idx = t; idx < 128*8; idx += 256){
    const int k = idx >> 3, x8 = (idx & 7)*8;
    uint4 vc, vs;
    vc.x = (u32)shc[(x8+0)*BPX+k] | ((u32)shc[(x8+1)*BPX+k] << 16);
    vc.y = (u32)shc[(x8+2)*BPX+k] | ((u32)shc[(x8+3)*BPX+k] << 16);
    vc.z = (u32)shc[(x8+4)*BPX+k] | ((u32)shc[(x8+5)*BPX+k] << 16);
    vc.w = (u32)shc[(x8+6)*BPX+k] | ((u32)shc[(x8+7)*BPX+k] << 16);
    vs.x = (u32)shs[(x8+0)*BPX+k] | ((u32)shs[(x8+1)*BPX+k] << 16);
    vs.y = (u32)shs[(x8+2)*BPX+k] | ((u32)shs[(x8+3)*BPX+k] << 16);
    vs.z = (u32)shs[(x8+4)*BPX+k] | ((u32)shs[(x8+5)*BPX+k] << 16);
    vs.w = (u32)shs[(x8+6)*BPX+k] | ((u32)shs[(x8+7)*BPX+k] << 16);
    const size_t dst = ((size_t)b*KK + k)*NN + x0 + x8;
    *(uint4*)&bc[dst] = vc;
    *(uint4*)&bs[dst] = vs;
  }
}

// ---------------------------------------------------------------- cvt
__global__ __launch_bounds__(256) void cvt_kernel(
    const float* __restrict__ convw, const float* __restrict__ fc1w,
    u16* __restrict__ cwb, u16* __restrict__ w1T)
{
  const int t = threadIdx.x;
  for (int i = t; i < LL*CC*CC; i += 256) cwb[i] = f2bf(convw[i]);
  for (int i = t; i < CC*CC; i += 256){
    const int f = i >> 7, c = i & 127;
    w1T[i] = f2bf(fc1w[(size_t)c*CC + f]);
  }
}

// ---------------------------------------------------------------- fc0 -> hT only
__global__ __launch_bounds__(256) void fc0_kernel(
    const float* __restrict__ X, const float* __restrict__ w, const float* __restrict__ bias,
    u16* __restrict__ hT)
{
  __shared__ float sxin[3*128];
  __shared__ float sw[3*128];
  __shared__ float sb[128];
  __shared__ u16 sht[128*BPX];
  const int b = blockIdx.x;
  const int x0 = blockIdx.y*128;
  const int t = threadIdx.x;
  if (t < 128){
    sb[t] = bias[t];
    #pragma unroll
    for (int j = 0; j < 3; ++j){
      sw[j*128 + t] = w[j*128 + t];
      sxin[j*128 + t] = X[((size_t)b*NN + x0 + t)*7 + j];
    }
  }
  __syncthreads();
  const int o = t >> 1;
  const int xh = (t & 1)*64;
  const float w0v = sw[o], w1v = sw[128+o], w2v = sw[256+o], bv = sb[o];
  for (int x = xh; x < xh + 64; ++x){
    sht[x*BPX + o] = f2bf(bv + sxin[x]*w0v + sxin[128+x]*w1v + sxin[256+x]*w2v);
  }
  __syncthreads();
  for (int idx = t; idx < 128*16; idx += 256){
    const int x = idx >> 4, c8 = (idx & 15)*8;
    *(uint4*)&hT[((size_t)b*NN + x0 + x)*CC + c8] = *(const uint4*)&sht[x*BPX + c8];
  }
}

// ---------------------------------------------------------------- proj (MFMA, m97-style)
// kind 0: xc[i][k] += sum_x hT[x][i]*s[x]*bc[k][x]; also x0[i] += sum_x h*s*m
// kind 1: xs[i][k] -= sum_x hT[x][i]*s[x]*bs[k][x]
__global__ __launch_bounds__(256) void proj_kernel(
    const u16* __restrict__ hT, const u16* __restrict__ bc, const u16* __restrict__ bs,
    const float* __restrict__ sA, const float* __restrict__ mA,
    float* __restrict__ xc, float* __restrict__ xs, float* __restrict__ x0a)
{
  __shared__ u16 sa[128*32];     // [i][x32] transposed+scaled A
  __shared__ u16 sb[128*32];     // [k][x32] B via global_load_lds
  __shared__ float ssc[512];
  __shared__ float smk[512];
  const int b = blockIdx.x;
  const int kind = blockIdx.y;
  const int z = blockIdx.z;            // 0..15, x-range of 512
  const int t = threadIdx.x;
  const int w = t >> 6, l = t & 63, lm = l & 15, q = l >> 4;
  const int xbase = z*512;
  const u16* Bsrc = (kind ? bs : bc) + (size_t)b*KK*NN + xbase;
  const u16* hTb  = hT + ((size_t)b*NN + xbase)*CC;
  for (int idx = t; idx < 512; idx += 256){
    ssc[idx] = sA[(size_t)b*NN + xbase + idx];
    smk[idx] = mA[(size_t)b*NN + xbase + idx];
  }
  const f32x4 z4 = {0.f,0.f,0.f,0.f};
  f32x4 acc[2][8];
  #pragma unroll
  for (int mt = 0; mt < 2; ++mt)
    #pragma unroll
    for (int nt = 0; nt < 8; ++nt) acc[mt][nt] = z4;
  float xac[8] = {0.f,0.f,0.f,0.f,0.f,0.f,0.f,0.f};
  const int xp = (t >> 4)*2;     // 0..30
  const int i8 = (t & 15)*8;
  __syncthreads();
  for (int cs = 0; cs < 16; ++cs){
    // async stage B tile [128k][32x]
    #pragma unroll
    for (int j = 0; j < 2; ++j){
      const int r = w*32 + j*16 + (l >> 2);
      gll16(Bsrc + (size_t)r*NN + cs*32 + (l & 3)*8, sb + (w*32 + j*16)*32);
    }
    // manual transpose+scale A: hT rows (32 x) -> sa[i][x32]
    const u16* r0 = hTb + (size_t)(cs*32 + xp)*CC + i8;
    const uint4 a0 = *(const uint4*)r0;
    const uint4 a1 = *(const uint4*)(r0 + CC);
    const float s0 = ssc[cs*32 + xp], s1 = ssc[cs*32 + xp + 1];
    const float m0 = smk[cs*32 + xp], m1 = smk[cs*32 + xp + 1];
    const u16* p0 = (const u16*)&a0;
    const u16* p1 = (const u16*)&a1;
    #pragma unroll
    for (int e = 0; e < 8; ++e){
      const float v0 = bf2f(p0[e])*s0;
      const float v1 = bf2f(p1[e])*s1;
      if (kind == 0) xac[e] += v0*m0 + v1*m1;
      *(u32*)&sa[(i8 + e)*32 + xp] = pk2(v0, v1);
    }
    __syncthreads();
    const bf16x8 af0 = *(const bf16x8*)&sa[(w*32      + lm)*32 + q*8];
    const bf16x8 af1 = *(const bf16x8*)&sa[(w*32 + 16 + lm)*32 + q*8];
    #pragma unroll
    for (int nt = 0; nt < 8; ++nt){
      const bf16x8 bf = *(const bf16x8*)&sb[(nt*16 + lm)*32 + q*8];
      acc[0][nt] = __builtin_amdgcn_mfma_f32_16x16x32_bf16(af0, bf, acc[0][nt], 0, 0, 0);
      acc[1][nt] = __builtin_amdgcn_mfma_f32_16x16x32_bf16(af1, bf, acc[1][nt], 0, 0, 0);
    }
    __syncthreads();
  }
  float* outp = kind ? xs : xc;
  const float sgn = kind ? -1.0f : 1.0f;
  #pragma unroll
  for (int mt = 0; mt < 2; ++mt){
    #pragma unroll
    for (int nt = 0; nt < 8; ++nt){
      const int k = nt*16 + lm;
      #pragma unroll
      for (int r = 0; r < 4; ++r){
        const int i = w*32 + mt*16 + q*4 + r;
        atomicAdd(&outp[((size_t)b*CC + i)*KK + k], sgn*acc[mt][nt][r]);
      }
    }
  }
  if (kind == 0){
    #pragma unroll
    for (int e = 0; e < 8; ++e){
      float v = xac[e];
      v += __shfl_xor(v, 16);
      v += __shfl_xor(v, 32);
      if (l < 16) atomicAdd(&x0a[b*CC + i8 + e], v);
    }
  }
}

// ---------------------------------------------------------------- mix
__global__ __launch_bounds__(256) void mix_kernel(
    const float* __restrict__ xc, const float* __restrict__ xs,
    const float* __restrict__ wcl, const float* __restrict__ wsl,
    u16* __restrict__ fcb, u16* __restrict__ fsb)
{
  const int b = blockIdx.x, og = blockIdx.y;
  const int t = threadIdx.x;
  const int k = t & 127, oh = t >> 7;
  const int o0 = og*8 + oh*4;
  float aC[4] = {0.f,0.f,0.f,0.f}, aS[4] = {0.f,0.f,0.f,0.f};
  const float* xcp = xc + (size_t)b*CC*KK + k;
  const float* xsp = xs + (size_t)b*CC*KK + k;
  const float* wcp = wcl + (size_t)o0*KK + k;
  const float* wsp = wsl + (size_t)o0*KK + k;
  for (int i = 0; i < CC; ++i){
    const float xcv = xcp[(size_t)i*KK];
    const float xsv = xsp[(size_t)i*KK];
    #pragma unroll
    for (int oo = 0; oo < 4; ++oo){
      const float a = wcp[((size_t)i*CC + oo)*KK];
      const float c = wsp[((size_t)i*CC + oo)*KK];
      aC[oo] += xcv*a - xsv*c;
      aS[oo] += xsv*a + xcv*c;
    }
  }
  const float sc = 2.0f/(float)NN;
  #pragma unroll
  for (int oo = 0; oo < 4; ++oo){
    fcb[((size_t)b*CC + o0+oo)*KK + k] = f2bf( aC[oo]*sc);
    fsb[((size_t)b*CC + o0+oo)*KK + k] = f2bf(-aS[oo]*sc);
  }
}

__global__ __launch_bounds__(128) void f0_kernel(
    const float* __restrict__ x0a, const float* __restrict__ w0l, float* __restrict__ f0b)
{
  const int b = blockIdx.x, o = threadIdx.x;
  float acc = 0.f;
  for (int i = 0; i < CC; ++i) acc += x0a[b*CC+i] * w0l[(size_t)i*CC + o];
  f0b[b*CC+o] = acc * (1.0f/(float)NN);
}

// ---------------------------------------------------------------- fused spectral+conv+gelu
__global__ __launch_bounds__(256) void fused_kernel(
    const u16* __restrict__ bcT, const u16* __restrict__ bsT, u16* __restrict__ hT,
    const u16* __restrict__ fcb, const u16* __restrict__ fsb,
    const u16* __restrict__ cwb, const float* __restrict__ cb,
    const float* __restrict__ f0b, const float* __restrict__ mA, const int act)
{
  __shared__ u16 smem[128*BPX];          // staging tiles, then [o][x] transpose
  __shared__ float sm[128], sf0[128], scb[128];
  u16* sa = smem;
  u16* sb = smem + 128*32;
  const int b  = blockIdx.x;
  const int x0 = blockIdx.y*128;
  const int t = threadIdx.x;
  const int w = t >> 6, l = t & 63, lm = l & 15, q = l >> 4;
  if (t < 128){
    sm[t]  = mA[(size_t)b*NN + x0 + t];
    sf0[t] = f0b[b*CC + t];
    scb[t] = cb[t];
  }
  const u16* Asrc0 = bcT + ((size_t)b*NN + x0)*KK;
  const u16* Asrc1 = bsT + ((size_t)b*NN + x0)*KK;
  const u16* Asrc2 = hT  + ((size_t)b*NN + x0)*CC;
  const u16* Bsrc0 = fcb + (size_t)b*CC*KK;
  const u16* Bsrc1 = fsb + (size_t)b*CC*KK;
  const f32x4 z4 = {0.f,0.f,0.f,0.f};
  f32x4 acc[2][8];
  #pragma unroll
  for (int mt = 0; mt < 2; ++mt)
    #pragma unroll
    for (int nt = 0; nt < 8; ++nt) acc[mt][nt] = z4;
  const int rr = l >> 2, c8 = (l & 3)*8;
  for (int s = 0; s < 12; ++s){
    const int g = s >> 2, kk = (s & 3)*32;
    const u16* Ap = (g == 0) ? Asrc0 : (g == 1) ? Asrc1 : Asrc2;
    const u16* Bp = (g == 0) ? Bsrc0 : (g == 1) ? Bsrc1 : cwb;
    #pragma unroll
    for (int j = 0; j < 2; ++j){
      const int r = w*32 + j*16 + rr;
      gll16(Ap + (size_t)r*128 + kk + c8, sa + (w*32 + j*16)*32);
      gll16(Bp + (size_t)r*128 + kk + c8, sb + (w*32 + j*16)*32);
    }
    __syncthreads();
    const bf16x8 af0 = *(const bf16x8*)&sa[(w*32      + lm)*32 + q*8];
    const bf16x8 af1 = *(const bf16x8*)&sa[(w*32 + 16 + lm)*32 + q*8];
    #pragma unroll
    for (int nt = 0; nt < 8; ++nt){
      const bf16x8 bf = *(const bf16x8*)&sb[(nt*16 + lm)*32 + q*8];
      acc[0][nt] = __builtin_amdgcn_mfma_f32_16x16x32_bf16(af0, bf, acc[0][nt], 0, 0, 0);
      acc[1][nt] = __builtin_amdgcn_mfma_f32_16x16x32_bf16(af1, bf, acc[1][nt], 0, 0, 0);
    }
    __syncthreads();
  }
  // epilogue: +f0*m + cb, gelu, pack into smem [o][x]
  #pragma unroll
  for (int mt = 0; mt < 2; ++mt){
    const int xb = w*32 + mt*16 + q*4;
    #pragma unroll
    for (int nt = 0; nt < 8; ++nt){
      const int o = nt*16 + lm;
      const float f0v = sf0[o], cbv = scb[o];
      ushort4 pk4;
      float v0 = acc[mt][nt][0] + f0v*sm[xb+0] + cbv;
      float v1 = acc[mt][nt][1] + f0v*sm[xb+1] + cbv;
      float v2 = acc[mt][nt][2] + f0v*sm[xb+2] + cbv;
      float v3 = acc[mt][nt][3] + f0v*sm[xb+3] + cbv;
      if (act){ v0 = gelu_f(v0); v1 = gelu_f(v1); v2 = gelu_f(v2); v3 = gelu_f(v3); }
      pk4.x = f2bf(v0); pk4.y = f2bf(v1); pk4.z = f2bf(v2); pk4.w = f2bf(v3);
      *(ushort4*)&smem[o*BPX + xb] = pk4;
    }
  }
  __syncthreads();
  // hT[x][o] in-place (block owns its x-rows)
  {
    const int x = t >> 1, oh = (t & 1)*64;
    #pragma unroll 2
    for (int j = 0; j < 8; ++j){
      const int ob = oh + j*8;
      uint4 qv;
      qv.x = (u32)smem[(ob+0)*BPX + x] | ((u32)smem[(ob+1)*BPX + x] << 16);
      qv.y = (u32)smem[(ob+2)*BPX + x] | ((u32)smem[(ob+3)*BPX + x] << 16);
      qv.z = (u32)smem[(ob+4)*BPX + x] | ((u32)smem[(ob+5)*BPX + x] << 16);
      qv.w = (u32)smem[(ob+6)*BPX + x] | ((u32)smem[(ob+7)*BPX + x] << 16);
      *(uint4*)&hT[((size_t)b*NN + x0 + x)*CC + ob] = qv;
    }
  }
}

// ---------------------------------------------------------------- final MLP (MFMA)
__global__ __launch_bounds__(256) void final_kernel(
    const u16* __restrict__ hT, const u16* __restrict__ w1T,
    const float* __restrict__ b1, const float* __restrict__ w2, const float* __restrict__ b2,
    float* __restrict__ out)
{
  __shared__ u16 sa[128*APX];
  __shared__ u16 sbt[128*APX];
  __shared__ float sb1[128], sw2[128];
  const int b  = blockIdx.x;
  const int x0 = blockIdx.y*128;
  const int t = threadIdx.x;
  const int w = t >> 6, l = t & 63, lm = l & 15, q = l >> 4;
  if (t < 128){ sb1[t] = b1[t]; sw2[t] = w2[t]; }
  const float b2v = b2[0];
  const f32x4 z4 = {0.f,0.f,0.f,0.f};
  f32x4 acc[2][8];
  #pragma unroll
  for (int mt = 0; mt < 2; ++mt)
    #pragma unroll
    for (int nt = 0; nt < 8; ++nt) acc[mt][nt] = z4;
  const u16* Ap = hT + ((size_t)b*NN + x0)*CC;
  const int row = t >> 2, ch = (t & 3)*8;
  for (int s = 0; s < 4; ++s){
    const int kk = s*32;
    __syncthreads();
    #pragma unroll
    for (int h = 0; h < 2; ++h){
      const int r = row + h*64;
      *(uint4*)&sa [r*APX + ch] = *(const uint4*)&Ap [(size_t)r*CC + kk + ch];
      *(uint4*)&sbt[r*APX + ch] = *(const uint4*)&w1T[(size_t)r*CC + kk + ch];
    }
    __syncthreads();
    bf16x8 af[2];
    af[0] = *(const bf16x8*)&sa[(w*32      + lm)*APX + q*8];
    af[1] = *(const bf16x8*)&sa[(w*32 + 16 + lm)*APX + q*8];
    #pragma unroll
    for (int nt = 0; nt < 8; ++nt){
      const bf16x8 bf = *(const bf16x8*)&sbt[(nt*16 + lm)*APX + q*8];
      acc[0][nt] = __builtin_amdgcn_mfma_f32_16x16x32_bf16(af[0], bf, acc[0][nt], 0, 0, 0);
      acc[1][nt] = __builtin_amdgcn_mfma_f32_16x16x32_bf16(af[1], bf, acc[1][nt], 0, 0, 0);
    }
  }
  #pragma unroll
  for (int mt = 0; mt < 2; ++mt){
    #pragma unroll
    for (int r = 0; r < 4; ++r){
      float s = 0.f;
      #pragma unroll
      for (int nt = 0; nt < 8; ++nt){
        const int f = nt*16 + lm;
        s += gelu_f(acc[mt][nt][r] + sb1[f]) * sw2[f];
      }
      s += __shfl_xor(s, 1);
      s += __shfl_xor(s, 2);
      s += __shfl_xor(s, 4);
      s += __shfl_xor(s, 8);
      if (lm == 0){
        const int x = x0 + w*32 + mt*16 + q*4 + r;
        out[(size_t)b*NN + x] = s + b2v;
      }
    }
  }
}

// ---------------------------------------------------------------- host
extern "C" void kernel_launch(void* const* d_in, const int* in_sizes, int n_in,
                              void* d_out, int out_size, void* d_ws, size_t ws_size,
                              hipStream_t stream)
{
  const float* X     = (const float*)d_in[0];
  const float* modes = (const float*)d_in[1];
  const float* fc0w  = (const float*)d_in[2];
  const float* fc0b  = (const float*)d_in[3];
  const float* wc    = (const float*)d_in[4];
  const float* wsm   = (const float*)d_in[5];
  const float* w0    = (const float*)d_in[6];
  const float* convw = (const float*)d_in[7];
  const float* convb = (const float*)d_in[8];
  const float* fc1w  = (const float*)d_in[9];
  const float* fc1b  = (const float*)d_in[10];
  const float* fc2w  = (const float*)d_in[11];
  const float* fc2b  = (const float*)d_in[12];
  float* out = (float*)d_out;

  const size_t nBKN = (size_t)BB*KK*NN;
  const size_t nBCK = (size_t)BB*CC*KK;
  const size_t nBC  = (size_t)BB*CC;
  const size_t nBN  = (size_t)BB*NN;

  char* p = (char*)d_ws;
  u16* bc  = (u16*)p; p += nBKN*2;
  u16* bs  = (u16*)p; p += nBKN*2;
  u16* bcT = (u16*)p; p += nBKN*2;
  u16* bsT = (u16*)p; p += nBKN*2;
  u16* hT  = (u16*)p; p += nBKN*2;
  float* xcA = (float*)p; p += nBCK*4;
  float* xsA = (float*)p; p += nBCK*4;
  float* x0A = (float*)p; p += nBC*4;
  u16* fcb = (u16*)p; p += nBCK*2;
  u16* fsb = (u16*)p; p += nBCK*2;
  float* f0b = (float*)p; p += nBC*4;
  float* mA  = (float*)p; p += nBN*4;
  float* sA  = (float*)p; p += nBN*4;
  u16* cwb = (u16*)p; p += (size_t)LL*CC*CC*2;
  u16* w1T = (u16*)p; p += (size_t)CC*CC*2;

  cvt_kernel<<<1, 256, 0, stream>>>(convw, fc1w, cwb, w1T);
  bases_kernel<<<dim3(BB, NN/64), 256, 0, stream>>>(X, modes, bc, bs, bcT, bsT, mA, sA);
  fc0_kernel<<<dim3(BB, NN/128), 256, 0, stream>>>(X, fc0w, fc0b, hT);

  for (int l = 0; l < LL; ++l){
    hipMemsetAsync(xcA, 0, (2*nBCK + nBC)*sizeof(float), stream);  // xc, xs, x0 contiguous
    proj_kernel<<<dim3(BB, 2, 16), 256, 0, stream>>>(hT, bc, bs, sA, mA, xcA, xsA, x0A);
    mix_kernel<<<dim3(BB, 16), 256, 0, stream>>>(xcA, xsA,
        wc + (size_t)l*CC*CC*KK, wsm + (size_t)l*CC*CC*KK, fcb, fsb);
    f0_kernel<<<dim3(BB), 128, 0, stream>>>(x0A, w0 + (size_t)l*CC*CC, f0b);
    fused_kernel<<<dim3(BB, NN/128), 256, 0, stream>>>(
        bcT, bsT, hT, fcb, fsb,
        cwb + (size_t)l*CC*CC, convb + (size_t)l*CC,
        f0b, mA, (l < LL-1) ? 1 : 0);
  }
  final_kernel<<<dim3(BB, NN/128), 256, 0, stream>>>(hT, w1T, fc1b, fc2w, fc2b, out);
}

// Round 4
// 989.640 us; speedup vs baseline: 1.0480x; 1.0480x over previous
//
#include <hip/hip_runtime.h>
#include <math.h>

#define BB 16
#define NN 8192
#define CC 128
#define KK 128
#define LL 4

#define APX 40    // padded LDS stride for final_kernel staging
#define BPX 136   // LDS row stride for 128-wide transpose tiles

typedef short bf16x8 __attribute__((ext_vector_type(8)));
typedef float f32x4 __attribute__((ext_vector_type(4)));

typedef unsigned short u16;
typedef unsigned int u32;

__device__ __forceinline__ float gelu_f(float v){ return 0.5f*v*(1.0f + erff(v*0.70710678118f)); }

__device__ __forceinline__ u16 f2bf(float f){
  u32 u = __float_as_uint(f);
  return (u16)((u + 0x7FFFu + ((u >> 16) & 1u)) >> 16);   // RNE
}
__device__ __forceinline__ float bf2f(u16 u){ return __uint_as_float(((u32)u) << 16); }
__device__ __forceinline__ u32 pk2(float a, float b){
  return (u32)f2bf(a) | ((u32)f2bf(b) << 16);
}

// async global->LDS, 16B per lane; LDS dst is wave-uniform base + lane*16
__device__ __forceinline__ void gll16(const u16* g, u16* l){
  __builtin_amdgcn_global_load_lds(
      (const __attribute__((address_space(1))) void*)g,
      (__attribute__((address_space(3))) void*)l, 16, 0, 0);
}

// ---------------------------------------------------------------- bases
// bcs[b][k][x] = cos(g.m_k)*mask*s   (s = w*N; scaled, for proj B)
// bcT[b][x][k] = cos(g.m_k)*mask     (unscaled, for fused A)   ; bss/bsT with sin
__global__ __launch_bounds__(256) void bases_kernel(
    const float* __restrict__ X, const float* __restrict__ modes,
    u16* __restrict__ bcs, u16* __restrict__ bss,
    u16* __restrict__ bcT, u16* __restrict__ bsT,
    float* __restrict__ mA, float* __restrict__ sm2)
{
  __shared__ float smodes[2*KK];
  __shared__ u16 shc[64*BPX];
  __shared__ u16 shs[64*BPX];
  __shared__ float ssv[64];
  const int b = blockIdx.x;
  const int x0 = blockIdx.y*64;
  const int t = threadIdx.x;
  smodes[t] = modes[t];
  const int xl = t & 63;
  const int kq = t >> 6;
  const int x = x0 + xl;
  const float* xp = X + ((size_t)b*NN + x)*7;
  const float g0 = xp[3], g1 = xp[4], wv = xp[5], mv = xp[6];
  const float sv = wv * (float)NN;
  if (kq == 0){
    mA[b*NN + x] = mv;
    sm2[b*NN + x] = mv * sv;
    ssv[xl] = sv;
  }
  __syncthreads();
  #pragma unroll 4
  for (int kk = 0; kk < 32; ++kk){
    const int k = kq*32 + kk;
    const float tt = g0*smodes[2*k] + g1*smodes[2*k+1];
    float sn, cs;
    __sincosf(tt, &sn, &cs);
    shc[xl*BPX + k] = f2bf(cs*mv);
    shs[xl*BPX + k] = f2bf(sn*mv);
  }
  __syncthreads();
  // [x][k] unscaled, coalesced
  for (int idx = t; idx < 64*16; idx += 256){
    const int row = idx >> 4, c16 = (idx & 15)*8;
    const size_t dst = ((size_t)b*NN + x0 + row)*KK + c16;
    *(uint4*)&bcT[dst] = *(const uint4*)&shc[row*BPX + c16];
    *(uint4*)&bsT[dst] = *(const uint4*)&shs[row*BPX + c16];
  }
  // [k][x] scaled by s
  for (int idx = t; idx < 128*8; idx += 256){
    const int k = idx >> 3, x8 = (idx & 7)*8;
    uint4 vc, vs;
    u32* pc = (u32*)&vc;
    u32* ps = (u32*)&vs;
    #pragma unroll
    for (int e = 0; e < 4; ++e){
      const int xa = x8 + 2*e, xb2 = x8 + 2*e + 1;
      const float sa = ssv[xa], sb = ssv[xb2];
      pc[e] = pk2(bf2f(shc[xa*BPX+k])*sa, bf2f(shc[xb2*BPX+k])*sb);
      ps[e] = pk2(bf2f(shs[xa*BPX+k])*sa, bf2f(shs[xb2*BPX+k])*sb);
    }
    const size_t dst = ((size_t)b*KK + k)*NN + x0 + x8;
    *(uint4*)&bcs[dst] = vc;
    *(uint4*)&bss[dst] = vs;
  }
}

// ---------------------------------------------------------------- cvt
__global__ __launch_bounds__(256) void cvt_kernel(
    const float* __restrict__ convw, const float* __restrict__ fc1w,
    u16* __restrict__ cwb, u16* __restrict__ w1T)
{
  const int t = threadIdx.x;
  for (int i = t; i < LL*CC*CC; i += 256) cwb[i] = f2bf(convw[i]);
  for (int i = t; i < CC*CC; i += 256){
    const int f = i >> 7, c = i & 127;
    w1T[i] = f2bf(fc1w[(size_t)c*CC + f]);
  }
}

// ---------------------------------------------------------------- fc0 -> hT, hI, x0[slot 0]
__global__ __launch_bounds__(256) void fc0_kernel(
    const float* __restrict__ X, const float* __restrict__ w, const float* __restrict__ bias,
    const float* __restrict__ sm2,
    u16* __restrict__ hT, u16* __restrict__ hI, float* __restrict__ x0out)
{
  __shared__ float sxin[3*128];
  __shared__ float sw[3*128];
  __shared__ float sb[128];
  __shared__ float ssm2[128];
  __shared__ u16 sht[128*BPX];   // [o][x]
  const int b = blockIdx.x;
  const int x0 = blockIdx.y*128;
  const int t = threadIdx.x;
  if (t < 128){
    sb[t] = bias[t];
    ssm2[t] = sm2[(size_t)b*NN + x0 + t];
    #pragma unroll
    for (int j = 0; j < 3; ++j){
      sw[j*128 + t] = w[j*128 + t];
      sxin[j*128 + t] = X[((size_t)b*NN + x0 + t)*7 + j];
    }
  }
  __syncthreads();
  const int o = t >> 1;
  const int xh = (t & 1)*64;
  const float w0v = sw[o], w1v = sw[128+o], w2v = sw[256+o], bv = sb[o];
  float xacc = 0.f;
  for (int x = xh; x < xh + 64; ++x){
    const float v = bv + sxin[x]*w0v + sxin[128+x]*w1v + sxin[256+x]*w2v;
    sht[o*BPX + x] = f2bf(v);
    xacc += v * ssm2[x];
  }
  xacc += __shfl_xor(xacc, 1);
  if ((t & 1) == 0) atomicAdd(&x0out[b*CC + o], xacc);
  __syncthreads();
  // hI[i][x] rows, coalesced
  for (int idx = t; idx < 128*16; idx += 256){
    const int o2 = idx >> 4, x8 = (idx & 15)*8;
    *(uint4*)&hI[((size_t)b*CC + o2)*NN + x0 + x8] = *(const uint4*)&sht[o2*BPX + x8];
  }
  // hT[x][c] transposed
  {
    const int x = t >> 1, oh = (t & 1)*64;
    #pragma unroll 2
    for (int j = 0; j < 8; ++j){
      const int ob = oh + j*8;
      uint4 qv;
      qv.x = (u32)sht[(ob+0)*BPX + x] | ((u32)sht[(ob+1)*BPX + x] << 16);
      qv.y = (u32)sht[(ob+2)*BPX + x] | ((u32)sht[(ob+3)*BPX + x] << 16);
      qv.z = (u32)sht[(ob+4)*BPX + x] | ((u32)sht[(ob+5)*BPX + x] << 16);
      qv.w = (u32)sht[(ob+6)*BPX + x] | ((u32)sht[(ob+7)*BPX + x] << 16);
      *(uint4*)&hT[((size_t)b*NN + x0 + x)*CC + ob] = qv;
    }
  }
}

// ---------------------------------------------------------------- proj: pure MFMA GEMM
// kind 0: xc[i][k] += sum_x hI[i][x]*bcs[k][x]
// kind 1: xs[i][k] -= sum_x hI[i][x]*bss[k][x]
__global__ __launch_bounds__(256) void proj_kernel(
    const u16* __restrict__ hI, const u16* __restrict__ bcs, const u16* __restrict__ bss,
    float* __restrict__ xc, float* __restrict__ xs)
{
  __shared__ u16 sa[128*32];     // [i][x32] via global_load_lds
  __shared__ u16 sb[128*32];     // [k][x32] via global_load_lds
  const int b = blockIdx.x;
  const int kind = blockIdx.y;
  const int z = blockIdx.z;            // 0..15, x-range of 512
  const int t = threadIdx.x;
  const int w = t >> 6, l = t & 63, lm = l & 15, q = l >> 4;
  const u16* Asrc = hI + (size_t)b*CC*NN + z*512;
  const u16* Bsrc = (kind ? bss : bcs) + (size_t)b*KK*NN + z*512;
  const f32x4 z4 = {0.f,0.f,0.f,0.f};
  f32x4 acc[2][8];
  #pragma unroll
  for (int mt = 0; mt < 2; ++mt)
    #pragma unroll
    for (int nt = 0; nt < 8; ++nt) acc[mt][nt] = z4;
  const int rr = l >> 2, c8 = (l & 3)*8;
  for (int cs = 0; cs < 16; ++cs){
    #pragma unroll
    for (int j = 0; j < 2; ++j){
      const int r = w*32 + j*16 + rr;
      gll16(Asrc + (size_t)r*NN + cs*32 + c8, sa + (w*32 + j*16)*32);
      gll16(Bsrc + (size_t)r*NN + cs*32 + c8, sb + (w*32 + j*16)*32);
    }
    __syncthreads();
    const bf16x8 af0 = *(const bf16x8*)&sa[(w*32      + lm)*32 + q*8];
    const bf16x8 af1 = *(const bf16x8*)&sa[(w*32 + 16 + lm)*32 + q*8];
    #pragma unroll
    for (int nt = 0; nt < 8; ++nt){
      const bf16x8 bf = *(const bf16x8*)&sb[(nt*16 + lm)*32 + q*8];
      acc[0][nt] = __builtin_amdgcn_mfma_f32_16x16x32_bf16(af0, bf, acc[0][nt], 0, 0, 0);
      acc[1][nt] = __builtin_amdgcn_mfma_f32_16x16x32_bf16(af1, bf, acc[1][nt], 0, 0, 0);
    }
    __syncthreads();
  }
  float* outp = kind ? xs : xc;
  const float sgn = kind ? -1.0f : 1.0f;
  #pragma unroll
  for (int mt = 0; mt < 2; ++mt){
    #pragma unroll
    for (int nt = 0; nt < 8; ++nt){
      const int k = nt*16 + lm;
      #pragma unroll
      for (int r = 0; r < 4; ++r){
        const int i = w*32 + mt*16 + q*4 + r;
        atomicAdd(&outp[((size_t)b*CC + i)*KK + k], sgn*acc[mt][nt][r]);
      }
    }
  }
}

// ---------------------------------------------------------------- mix
__global__ __launch_bounds__(256) void mix_kernel(
    const float* __restrict__ xc, const float* __restrict__ xs,
    const float* __restrict__ wcl, const float* __restrict__ wsl,
    u16* __restrict__ fcb, u16* __restrict__ fsb)
{
  const int b = blockIdx.x, og = blockIdx.y;
  const int t = threadIdx.x;
  const int k = t & 127, oh = t >> 7;
  const int o0 = og*8 + oh*4;
  float aC[4] = {0.f,0.f,0.f,0.f}, aS[4] = {0.f,0.f,0.f,0.f};
  const float* xcp = xc + (size_t)b*CC*KK + k;
  const float* xsp = xs + (size_t)b*CC*KK + k;
  const float* wcp = wcl + (size_t)o0*KK + k;
  const float* wsp = wsl + (size_t)o0*KK + k;
  for (int i = 0; i < CC; ++i){
    const float xcv = xcp[(size_t)i*KK];
    const float xsv = xsp[(size_t)i*KK];
    #pragma unroll
    for (int oo = 0; oo < 4; ++oo){
      const float a = wcp[((size_t)i*CC + oo)*KK];
      const float c = wsp[((size_t)i*CC + oo)*KK];
      aC[oo] += xcv*a - xsv*c;
      aS[oo] += xsv*a + xcv*c;
    }
  }
  const float sc = 2.0f/(float)NN;
  #pragma unroll
  for (int oo = 0; oo < 4; ++oo){
    fcb[((size_t)b*CC + o0+oo)*KK + k] = f2bf( aC[oo]*sc);
    fsb[((size_t)b*CC + o0+oo)*KK + k] = f2bf(-aS[oo]*sc);
  }
}

__global__ __launch_bounds__(128) void f0_kernel(
    const float* __restrict__ x0a, const float* __restrict__ w0l, float* __restrict__ f0b)
{
  const int b = blockIdx.x, o = threadIdx.x;
  float acc = 0.f;
  for (int i = 0; i < CC; ++i) acc += x0a[b*CC+i] * w0l[(size_t)i*CC + o];
  f0b[b*CC+o] = acc * (1.0f/(float)NN);
}

// ---------------------------------------------------------------- fused spectral+conv+gelu
__global__ __launch_bounds__(256) void fused_kernel(
    const u16* __restrict__ bcT, const u16* __restrict__ bsT, u16* __restrict__ hT,
    const u16* __restrict__ fcb, const u16* __restrict__ fsb,
    const u16* __restrict__ cwb, const float* __restrict__ cb,
    const float* __restrict__ f0b, const float* __restrict__ mA, const float* __restrict__ sm2,
    u16* __restrict__ hI, float* __restrict__ x0next, const int act)
{
  __shared__ u16 smem[128*BPX];          // staging tiles, then [o][x] result
  __shared__ float sm[128], sf0[128], scb[128], ssm2[128];
  u16* sa = smem;
  u16* sb = smem + 128*32;
  const int b  = blockIdx.x;
  const int x0 = blockIdx.y*128;
  const int t = threadIdx.x;
  const int w = t >> 6, l = t & 63, lm = l & 15, q = l >> 4;
  if (t < 128){
    sm[t]   = mA[(size_t)b*NN + x0 + t];
    sf0[t]  = f0b[b*CC + t];
    scb[t]  = cb[t];
    ssm2[t] = sm2[(size_t)b*NN + x0 + t];
  }
  const u16* Asrc0 = bcT + ((size_t)b*NN + x0)*KK;
  const u16* Asrc1 = bsT + ((size_t)b*NN + x0)*KK;
  const u16* Asrc2 = hT  + ((size_t)b*NN + x0)*CC;
  const u16* Bsrc0 = fcb + (size_t)b*CC*KK;
  const u16* Bsrc1 = fsb + (size_t)b*CC*KK;
  const f32x4 z4 = {0.f,0.f,0.f,0.f};
  f32x4 acc[2][8];
  #pragma unroll
  for (int mt = 0; mt < 2; ++mt)
    #pragma unroll
    for (int nt = 0; nt < 8; ++nt) acc[mt][nt] = z4;
  const int rr = l >> 2, c8 = (l & 3)*8;
  for (int s = 0; s < 12; ++s){
    const int g = s >> 2, kk = (s & 3)*32;
    const u16* Ap = (g == 0) ? Asrc0 : (g == 1) ? Asrc1 : Asrc2;
    const u16* Bp = (g == 0) ? Bsrc0 : (g == 1) ? Bsrc1 : cwb;
    #pragma unroll
    for (int j = 0; j < 2; ++j){
      const int r = w*32 + j*16 + rr;
      gll16(Ap + (size_t)r*128 + kk + c8, sa + (w*32 + j*16)*32);
      gll16(Bp + (size_t)r*128 + kk + c8, sb + (w*32 + j*16)*32);
    }
    __syncthreads();
    const bf16x8 af0 = *(const bf16x8*)&sa[(w*32      + lm)*32 + q*8];
    const bf16x8 af1 = *(const bf16x8*)&sa[(w*32 + 16 + lm)*32 + q*8];
    #pragma unroll
    for (int nt = 0; nt < 8; ++nt){
      const bf16x8 bf = *(const bf16x8*)&sb[(nt*16 + lm)*32 + q*8];
      acc[0][nt] = __builtin_amdgcn_mfma_f32_16x16x32_bf16(af0, bf, acc[0][nt], 0, 0, 0);
      acc[1][nt] = __builtin_amdgcn_mfma_f32_16x16x32_bf16(af1, bf, acc[1][nt], 0, 0, 0);
    }
    __syncthreads();
  }
  // epilogue: +f0*m + cb, gelu, pack into smem [o][x]
  #pragma unroll
  for (int mt = 0; mt < 2; ++mt){
    const int xb = w*32 + mt*16 + q*4;
    #pragma unroll
    for (int nt = 0; nt < 8; ++nt){
      const int o = nt*16 + lm;
      const float f0v = sf0[o], cbv = scb[o];
      ushort4 pk4;
      float v0 = acc[mt][nt][0] + f0v*sm[xb+0] + cbv;
      float v1 = acc[mt][nt][1] + f0v*sm[xb+1] + cbv;
      float v2 = acc[mt][nt][2] + f0v*sm[xb+2] + cbv;
      float v3 = acc[mt][nt][3] + f0v*sm[xb+3] + cbv;
      if (act){ v0 = gelu_f(v0); v1 = gelu_f(v1); v2 = gelu_f(v2); v3 = gelu_f(v3); }
      pk4.x = f2bf(v0); pk4.y = f2bf(v1); pk4.z = f2bf(v2); pk4.w = f2bf(v3);
      *(ushort4*)&smem[o*BPX + xb] = pk4;
    }
  }
  __syncthreads();
  // hI[i][x] rows + x0 partial (only when another layer follows)
  if (act){
    const int o = t >> 1, xh = (t & 1)*64;
    float xacc = 0.f;
    #pragma unroll 2
    for (int j = 0; j < 8; ++j){
      const int x8 = xh + j*8;
      const uint4 rv = *(const uint4*)&smem[o*BPX + x8];
      *(uint4*)&hI[((size_t)b*CC + o)*NN + x0 + x8] = rv;
      xacc += bf2f((u16)(rv.x & 0xffff))*ssm2[x8+0] + bf2f((u16)(rv.x >> 16))*ssm2[x8+1]
            + bf2f((u16)(rv.y & 0xffff))*ssm2[x8+2] + bf2f((u16)(rv.y >> 16))*ssm2[x8+3]
            + bf2f((u16)(rv.z & 0xffff))*ssm2[x8+4] + bf2f((u16)(rv.z >> 16))*ssm2[x8+5]
            + bf2f((u16)(rv.w & 0xffff))*ssm2[x8+6] + bf2f((u16)(rv.w >> 16))*ssm2[x8+7];
    }
    xacc += __shfl_xor(xacc, 1);
    if ((t & 1) == 0) atomicAdd(&x0next[b*CC + o], xacc);
  }
  // hT[x][o] in-place (block owns its x-rows)
  {
    const int x = t >> 1, oh = (t & 1)*64;
    #pragma unroll 2
    for (int j = 0; j < 8; ++j){
      const int ob = oh + j*8;
      uint4 qv;
      qv.x = (u32)smem[(ob+0)*BPX + x] | ((u32)smem[(ob+1)*BPX + x] << 16);
      qv.y = (u32)smem[(ob+2)*BPX + x] | ((u32)smem[(ob+3)*BPX + x] << 16);
      qv.z = (u32)smem[(ob+4)*BPX + x] | ((u32)smem[(ob+5)*BPX + x] << 16);
      qv.w = (u32)smem[(ob+6)*BPX + x] | ((u32)smem[(ob+7)*BPX + x] << 16);
      *(uint4*)&hT[((size_t)b*NN + x0 + x)*CC + ob] = qv;
    }
  }
}

// ---------------------------------------------------------------- final MLP (MFMA)
__global__ __launch_bounds__(256) void final_kernel(
    const u16* __restrict__ hT, const u16* __restrict__ w1T,
    const float* __restrict__ b1, const float* __restrict__ w2, const float* __restrict__ b2,
    float* __restrict__ out)
{
  __shared__ u16 sa[128*APX];
  __shared__ u16 sbt[128*APX];
  __shared__ float sb1[128], sw2[128];
  const int b  = blockIdx.x;
  const int x0 = blockIdx.y*128;
  const int t = threadIdx.x;
  const int w = t >> 6, l = t & 63, lm = l & 15, q = l >> 4;
  if (t < 128){ sb1[t] = b1[t]; sw2[t] = w2[t]; }
  const float b2v = b2[0];
  const f32x4 z4 = {0.f,0.f,0.f,0.f};
  f32x4 acc[2][8];
  #pragma unroll
  for (int mt = 0; mt < 2; ++mt)
    #pragma unroll
    for (int nt = 0; nt < 8; ++nt) acc[mt][nt] = z4;
  const u16* Ap = hT + ((size_t)b*NN + x0)*CC;
  const int row = t >> 2, ch = (t & 3)*8;
  for (int s = 0; s < 4; ++s){
    const int kk = s*32;
    __syncthreads();
    #pragma unroll
    for (int h = 0; h < 2; ++h){
      const int r = row + h*64;
      *(uint4*)&sa [r*APX + ch] = *(const uint4*)&Ap [(size_t)r*CC + kk + ch];
      *(uint4*)&sbt[r*APX + ch] = *(const uint4*)&w1T[(size_t)r*CC + kk + ch];
    }
    __syncthreads();
    bf16x8 af[2];
    af[0] = *(const bf16x8*)&sa[(w*32      + lm)*APX + q*8];
    af[1] = *(const bf16x8*)&sa[(w*32 + 16 + lm)*APX + q*8];
    #pragma unroll
    for (int nt = 0; nt < 8; ++nt){
      const bf16x8 bf = *(const bf16x8*)&sbt[(nt*16 + lm)*APX + q*8];
      acc[0][nt] = __builtin_amdgcn_mfma_f32_16x16x32_bf16(af[0], bf, acc[0][nt], 0, 0, 0);
      acc[1][nt] = __builtin_amdgcn_mfma_f32_16x16x32_bf16(af[1], bf, acc[1][nt], 0, 0, 0);
    }
  }
  #pragma unroll
  for (int mt = 0; mt < 2; ++mt){
    #pragma unroll
    for (int r = 0; r < 4; ++r){
      float s = 0.f;
      #pragma unroll
      for (int nt = 0; nt < 8; ++nt){
        const int f = nt*16 + lm;
        s += gelu_f(acc[mt][nt][r] + sb1[f]) * sw2[f];
      }
      s += __shfl_xor(s, 1);
      s += __shfl_xor(s, 2);
      s += __shfl_xor(s, 4);
      s += __shfl_xor(s, 8);
      if (lm == 0){
        const int x = x0 + w*32 + mt*16 + q*4 + r;
        out[(size_t)b*NN + x] = s + b2v;
      }
    }
  }
}

// ---------------------------------------------------------------- host
extern "C" void kernel_launch(void* const* d_in, const int* in_sizes, int n_in,
                              void* d_out, int out_size, void* d_ws, size_t ws_size,
                              hipStream_t stream)
{
  const float* X     = (const float*)d_in[0];
  const float* modes = (const float*)d_in[1];
  const float* fc0w  = (const float*)d_in[2];
  const float* fc0b  = (const float*)d_in[3];
  const float* wc    = (const float*)d_in[4];
  const float* wsm   = (const float*)d_in[5];
  const float* w0    = (const float*)d_in[6];
  const float* convw = (const float*)d_in[7];
  const float* convb = (const float*)d_in[8];
  const float* fc1w  = (const float*)d_in[9];
  const float* fc1b  = (const float*)d_in[10];
  const float* fc2w  = (const float*)d_in[11];
  const float* fc2b  = (const float*)d_in[12];
  float* out = (float*)d_out;

  const size_t nBKN = (size_t)BB*KK*NN;
  const size_t nBCK = (size_t)BB*CC*KK;
  const size_t nBC  = (size_t)BB*CC;
  const size_t nBN  = (size_t)BB*NN;

  char* p = (char*)d_ws;
  u16* bcs = (u16*)p; p += nBKN*2;
  u16* bss = (u16*)p; p += nBKN*2;
  u16* bcT = (u16*)p; p += nBKN*2;
  u16* bsT = (u16*)p; p += nBKN*2;
  u16* hI  = (u16*)p; p += nBKN*2;
  u16* hT  = (u16*)p; p += nBKN*2;
  float* xcA = (float*)p; p += nBCK*4;
  float* xsA = (float*)p; p += nBCK*4;
  float* x0A = (float*)p; p += 4*nBC*4;    // 4 per-layer slots
  u16* fcb = (u16*)p; p += nBCK*2;
  u16* fsb = (u16*)p; p += nBCK*2;
  float* f0b = (float*)p; p += nBC*4;
  float* mA  = (float*)p; p += nBN*4;
  float* sm2 = (float*)p; p += nBN*4;
  u16* cwb = (u16*)p; p += (size_t)LL*CC*CC*2;
  u16* w1T = (u16*)p; p += (size_t)CC*CC*2;

  hipMemsetAsync(x0A, 0, 4*nBC*sizeof(float), stream);
  cvt_kernel<<<1, 256, 0, stream>>>(convw, fc1w, cwb, w1T);
  bases_kernel<<<dim3(BB, NN/64), 256, 0, stream>>>(X, modes, bcs, bss, bcT, bsT, mA, sm2);
  fc0_kernel<<<dim3(BB, NN/128), 256, 0, stream>>>(X, fc0w, fc0b, sm2, hT, hI, x0A);

  for (int l = 0; l < LL; ++l){
    hipMemsetAsync(xcA, 0, 2*nBCK*sizeof(float), stream);   // xc | xs contiguous
    proj_kernel<<<dim3(BB, 2, 16), 256, 0, stream>>>(hI, bcs, bss, xcA, xsA);
    mix_kernel<<<dim3(BB, 16), 256, 0, stream>>>(xcA, xsA,
        wc + (size_t)l*CC*CC*KK, wsm + (size_t)l*CC*CC*KK, fcb, fsb);
    f0_kernel<<<dim3(BB), 128, 0, stream>>>(x0A + (size_t)l*nBC, w0 + (size_t)l*CC*CC, f0b);
    fused_kernel<<<dim3(BB, NN/128), 256, 0, stream>>>(
        bcT, bsT, hT, fcb, fsb,
        cwb + (size_t)l*CC*CC, convb + (size_t)l*CC,
        f0b, mA, sm2, hI,
        x0A + (size_t)(l+1 < LL ? l+1 : 0)*nBC,   // unused when act==0
        (l < LL-1) ? 1 : 0);
  }
  final_kernel<<<dim3(BB, NN/128), 256, 0, stream>>>(hT, w1T, fc1b, fc2w, fc2b, out);
}

// Round 5
// 841.469 us; speedup vs baseline: 1.2326x; 1.1761x over previous
//
#include <hip/hip_runtime.h>
#include <math.h>

#define BB 16
#define NN 8192
#define CC 128
#define KK 128
#define LL 4

#define APX 40    // padded LDS stride for final_kernel staging
#define BPX 136   // LDS row stride for 128-wide transpose tiles

typedef short bf16x8 __attribute__((ext_vector_type(8)));
typedef float f32x4 __attribute__((ext_vector_type(4)));

typedef unsigned short u16;
typedef unsigned int u32;

__device__ __forceinline__ float gelu_f(float v){ return 0.5f*v*(1.0f + erff(v*0.70710678118f)); }

__device__ __forceinline__ u16 f2bf(float f){
  u32 u = __float_as_uint(f);
  return (u16)((u + 0x7FFFu + ((u >> 16) & 1u)) >> 16);   // RNE
}
__device__ __forceinline__ float bf2f(u16 u){ return __uint_as_float(((u32)u) << 16); }
__device__ __forceinline__ u32 pk2(float a, float b){
  return (u32)f2bf(a) | ((u32)f2bf(b) << 16);
}

// async global->LDS, 16B per lane; LDS dst is wave-uniform base + lane*16
__device__ __forceinline__ void gll16(const u16* g, u16* l){
  __builtin_amdgcn_global_load_lds(
      (const __attribute__((address_space(1))) void*)g,
      (__attribute__((address_space(3))) void*)l, 16, 0, 0);
}

// ---------------------------------------------------------------- bases
// bcs[b][k][x] = cos(g.m_k)*mask*s   (s = w*N; scaled, for proj B)
// bcT[b][x][k] = cos(g.m_k)*mask     (unscaled, for fused A)   ; bss/bsT with sin
__global__ __launch_bounds__(256) void bases_kernel(
    const float* __restrict__ X, const float* __restrict__ modes,
    u16* __restrict__ bcs, u16* __restrict__ bss,
    u16* __restrict__ bcT, u16* __restrict__ bsT,
    float* __restrict__ mA, float* __restrict__ sm2)
{
  __shared__ float smodes[2*KK];
  __shared__ u16 shc[64*BPX];
  __shared__ u16 shs[64*BPX];
  __shared__ float ssv[64];
  const int b = blockIdx.x;
  const int x0 = blockIdx.y*64;
  const int t = threadIdx.x;
  smodes[t] = modes[t];
  const int xl = t & 63;
  const int kq = t >> 6;
  const int x = x0 + xl;
  const float* xp = X + ((size_t)b*NN + x)*7;
  const float g0 = xp[3], g1 = xp[4], wv = xp[5], mv = xp[6];
  const float sv = wv * (float)NN;
  if (kq == 0){
    mA[b*NN + x] = mv;
    sm2[b*NN + x] = mv * sv;
    ssv[xl] = sv;
  }
  __syncthreads();
  #pragma unroll 4
  for (int kk = 0; kk < 32; ++kk){
    const int k = kq*32 + kk;
    const float tt = g0*smodes[2*k] + g1*smodes[2*k+1];
    float sn, cs;
    __sincosf(tt, &sn, &cs);
    shc[xl*BPX + k] = f2bf(cs*mv);
    shs[xl*BPX + k] = f2bf(sn*mv);
  }
  __syncthreads();
  // [x][k] unscaled, coalesced
  for (int idx = t; idx < 64*16; idx += 256){
    const int row = idx >> 4, c16 = (idx & 15)*8;
    const size_t dst = ((size_t)b*NN + x0 + row)*KK + c16;
    *(uint4*)&bcT[dst] = *(const uint4*)&shc[row*BPX + c16];
    *(uint4*)&bsT[dst] = *(const uint4*)&shs[row*BPX + c16];
  }
  // [k][x] scaled by s
  for (int idx = t; idx < 128*8; idx += 256){
    const int k = idx >> 3, x8 = (idx & 7)*8;
    uint4 vc, vs;
    u32* pc = (u32*)&vc;
    u32* ps = (u32*)&vs;
    #pragma unroll
    for (int e = 0; e < 4; ++e){
      const int xa = x8 + 2*e, xb2 = x8 + 2*e + 1;
      const float sa = ssv[xa], sb = ssv[xb2];
      pc[e] = pk2(bf2f(shc[xa*BPX+k])*sa, bf2f(shc[xb2*BPX+k])*sb);
      ps[e] = pk2(bf2f(shs[xa*BPX+k])*sa, bf2f(shs[xb2*BPX+k])*sb);
    }
    const size_t dst = ((size_t)b*KK + k)*NN + x0 + x8;
    *(uint4*)&bcs[dst] = vc;
    *(uint4*)&bss[dst] = vs;
  }
}

// ---------------------------------------------------------------- cvt
__global__ __launch_bounds__(256) void cvt_kernel(
    const float* __restrict__ convw, const float* __restrict__ fc1w,
    u16* __restrict__ cwb, u16* __restrict__ w1T)
{
  const int t = threadIdx.x;
  for (int i = t; i < LL*CC*CC; i += 256) cwb[i] = f2bf(convw[i]);
  for (int i = t; i < CC*CC; i += 256){
    const int f = i >> 7, c = i & 127;
    w1T[i] = f2bf(fc1w[(size_t)c*CC + f]);
  }
}

// ---------------------------------------------------------------- fc0 -> hT, hI, x0[slot 0]
__global__ __launch_bounds__(256) void fc0_kernel(
    const float* __restrict__ X, const float* __restrict__ w, const float* __restrict__ bias,
    const float* __restrict__ sm2,
    u16* __restrict__ hT, u16* __restrict__ hI, float* __restrict__ x0out)
{
  __shared__ float sxin[3*128];
  __shared__ float sw[3*128];
  __shared__ float sb[128];
  __shared__ float ssm2[128];
  __shared__ u16 sht[128*BPX];   // [o][x]
  const int b = blockIdx.x;
  const int x0 = blockIdx.y*128;
  const int t = threadIdx.x;
  if (t < 128){
    sb[t] = bias[t];
    ssm2[t] = sm2[(size_t)b*NN + x0 + t];
    #pragma unroll
    for (int j = 0; j < 3; ++j){
      sw[j*128 + t] = w[j*128 + t];
      sxin[j*128 + t] = X[((size_t)b*NN + x0 + t)*7 + j];
    }
  }
  __syncthreads();
  const int o = t >> 1;
  const int xh = (t & 1)*64;
  const float w0v = sw[o], w1v = sw[128+o], w2v = sw[256+o], bv = sb[o];
  float xacc = 0.f;
  for (int x = xh; x < xh + 64; ++x){
    const float v = bv + sxin[x]*w0v + sxin[128+x]*w1v + sxin[256+x]*w2v;
    sht[o*BPX + x] = f2bf(v);
    xacc += v * ssm2[x];
  }
  xacc += __shfl_xor(xacc, 1);
  if ((t & 1) == 0) atomicAdd(&x0out[b*CC + o], xacc);
  __syncthreads();
  // hI[i][x] rows, coalesced
  for (int idx = t; idx < 128*16; idx += 256){
    const int o2 = idx >> 4, x8 = (idx & 15)*8;
    *(uint4*)&hI[((size_t)b*CC + o2)*NN + x0 + x8] = *(const uint4*)&sht[o2*BPX + x8];
  }
  // hT[x][c] transposed
  {
    const int x = t >> 1, oh = (t & 1)*64;
    #pragma unroll 2
    for (int j = 0; j < 8; ++j){
      const int ob = oh + j*8;
      uint4 qv;
      qv.x = (u32)sht[(ob+0)*BPX + x] | ((u32)sht[(ob+1)*BPX + x] << 16);
      qv.y = (u32)sht[(ob+2)*BPX + x] | ((u32)sht[(ob+3)*BPX + x] << 16);
      qv.z = (u32)sht[(ob+4)*BPX + x] | ((u32)sht[(ob+5)*BPX + x] << 16);
      qv.w = (u32)sht[(ob+6)*BPX + x] | ((u32)sht[(ob+7)*BPX + x] << 16);
      *(uint4*)&hT[((size_t)b*NN + x0 + x)*CC + ob] = qv;
    }
  }
}

// ---------------------------------------------------------------- proj: merged cos+sin MFMA GEMM, dbuf
// xc[i][k] += sum_x hI[i][x]*bcs[k][x] ;  xs[i][k] -= sum_x hI[i][x]*bss[k][x]
__global__ __launch_bounds__(256) void proj_kernel(
    const u16* __restrict__ hI, const u16* __restrict__ bcs, const u16* __restrict__ bss,
    float* __restrict__ xc, float* __restrict__ xs)
{
  __shared__ u16 sa [2][128*32];
  __shared__ u16 sbc[2][128*32];
  __shared__ u16 sbs[2][128*32];
  const int b = blockIdx.x;
  const int z = blockIdx.y;            // 0..15, x-range of 512
  const int t = threadIdx.x;
  const int w = t >> 6, l = t & 63, lm = l & 15, q = l >> 4;
  const int rr = l >> 2, c8 = (l & 3)*8;
  const u16* Asrc = hI + (size_t)b*CC*NN + z*512;
  const u16* Bc   = bcs + (size_t)b*KK*NN + z*512;
  const u16* Bs   = bss + (size_t)b*KK*NN + z*512;
  const f32x4 z4 = {0.f,0.f,0.f,0.f};
  f32x4 accC[2][8], accS[2][8];
  #pragma unroll
  for (int mt = 0; mt < 2; ++mt)
    #pragma unroll
    for (int nt = 0; nt < 8; ++nt){ accC[mt][nt] = z4; accS[mt][nt] = z4; }

  // prologue: stage chunk 0 into buf 0
  #pragma unroll
  for (int j = 0; j < 2; ++j){
    const int r = w*32 + j*16 + rr;
    gll16(Asrc + (size_t)r*NN + c8, sa [0] + (w*32 + j*16)*32);
    gll16(Bc   + (size_t)r*NN + c8, sbc[0] + (w*32 + j*16)*32);
    gll16(Bs   + (size_t)r*NN + c8, sbs[0] + (w*32 + j*16)*32);
  }
  for (int cs = 0; cs < 16; ++cs){
    __syncthreads();                       // buf[cs&1] DMA drained here
    const int cur = cs & 1;
    if (cs < 15){                          // prefetch next chunk (overlaps MFMA below)
      const int nb = cur ^ 1;
      const int c2 = (cs + 1)*32;
      #pragma unroll
      for (int j = 0; j < 2; ++j){
        const int r = w*32 + j*16 + rr;
        gll16(Asrc + (size_t)r*NN + c2 + c8, sa [nb] + (w*32 + j*16)*32);
        gll16(Bc   + (size_t)r*NN + c2 + c8, sbc[nb] + (w*32 + j*16)*32);
        gll16(Bs   + (size_t)r*NN + c2 + c8, sbs[nb] + (w*32 + j*16)*32);
      }
    }
    const bf16x8 af0 = *(const bf16x8*)&sa[cur][(w*32      + lm)*32 + q*8];
    const bf16x8 af1 = *(const bf16x8*)&sa[cur][(w*32 + 16 + lm)*32 + q*8];
    #pragma unroll
    for (int nt = 0; nt < 8; ++nt){
      const bf16x8 bfc = *(const bf16x8*)&sbc[cur][(nt*16 + lm)*32 + q*8];
      const bf16x8 bfs = *(const bf16x8*)&sbs[cur][(nt*16 + lm)*32 + q*8];
      accC[0][nt] = __builtin_amdgcn_mfma_f32_16x16x32_bf16(af0, bfc, accC[0][nt], 0, 0, 0);
      accC[1][nt] = __builtin_amdgcn_mfma_f32_16x16x32_bf16(af1, bfc, accC[1][nt], 0, 0, 0);
      accS[0][nt] = __builtin_amdgcn_mfma_f32_16x16x32_bf16(af0, bfs, accS[0][nt], 0, 0, 0);
      accS[1][nt] = __builtin_amdgcn_mfma_f32_16x16x32_bf16(af1, bfs, accS[1][nt], 0, 0, 0);
    }
  }
  #pragma unroll
  for (int mt = 0; mt < 2; ++mt){
    #pragma unroll
    for (int nt = 0; nt < 8; ++nt){
      const int k = nt*16 + lm;
      #pragma unroll
      for (int r = 0; r < 4; ++r){
        const int i = w*32 + mt*16 + q*4 + r;
        atomicAdd(&xc[((size_t)b*CC + i)*KK + k],  accC[mt][nt][r]);
        atomicAdd(&xs[((size_t)b*CC + i)*KK + k], -accS[mt][nt][r]);
      }
    }
  }
}

// ---------------------------------------------------------------- mix (k-split grid)
__global__ __launch_bounds__(256) void mix_kernel(
    const float* __restrict__ xc, const float* __restrict__ xs,
    const float* __restrict__ wcl, const float* __restrict__ wsl,
    u16* __restrict__ fcb, u16* __restrict__ fsb)
{
  const int b = blockIdx.x, gy = blockIdx.y;   // gy 0..31
  const int og = gy >> 1, kh = gy & 1;
  const int t = threadIdx.x;
  const int k = kh*64 + (t & 63);
  const int oh = t >> 6;                       // 0..3
  const int o0 = og*8 + oh*2;
  float aC[2] = {0.f,0.f}, aS[2] = {0.f,0.f};
  const float* xcp = xc + (size_t)b*CC*KK + k;
  const float* xsp = xs + (size_t)b*CC*KK + k;
  const float* wcp = wcl + (size_t)o0*KK + k;
  const float* wsp = wsl + (size_t)o0*KK + k;
  for (int i = 0; i < CC; ++i){
    const float xcv = xcp[(size_t)i*KK];
    const float xsv = xsp[(size_t)i*KK];
    #pragma unroll
    for (int oo = 0; oo < 2; ++oo){
      const float a = wcp[((size_t)i*CC + oo)*KK];
      const float c = wsp[((size_t)i*CC + oo)*KK];
      aC[oo] += xcv*a - xsv*c;
      aS[oo] += xsv*a + xcv*c;
    }
  }
  const float sc = 2.0f/(float)NN;
  #pragma unroll
  for (int oo = 0; oo < 2; ++oo){
    fcb[((size_t)b*CC + o0+oo)*KK + k] = f2bf( aC[oo]*sc);
    fsb[((size_t)b*CC + o0+oo)*KK + k] = f2bf(-aS[oo]*sc);
  }
}

__global__ __launch_bounds__(128) void f0_kernel(
    const float* __restrict__ x0a, const float* __restrict__ w0l, float* __restrict__ f0b)
{
  const int b = blockIdx.x, o = threadIdx.x;
  float acc = 0.f;
  for (int i = 0; i < CC; ++i) acc += x0a[b*CC+i] * w0l[(size_t)i*CC + o];
  f0b[b*CC+o] = acc * (1.0f/(float)NN);
}

// ---------------------------------------------------------------- fused spectral+conv+gelu (dbuf)
__global__ __launch_bounds__(256) void fused_kernel(
    const u16* __restrict__ bcT, const u16* __restrict__ bsT, u16* __restrict__ hT,
    const u16* __restrict__ fcb, const u16* __restrict__ fsb,
    const u16* __restrict__ cwb, const float* __restrict__ cb,
    const float* __restrict__ f0b, const float* __restrict__ mA, const float* __restrict__ sm2,
    u16* __restrict__ hI, float* __restrict__ x0next, const int act)
{
  // union: staging dbuf (2 x (A 4096 + B 4096) u16 = 16384 u16) overlaid with
  // result [x][o] stride BPX (128*136 = 17408 u16)
  __shared__ u16 smem[128*BPX];
  __shared__ float sm[128], sf0[128], scb[128], ssm2[128];
  const int b  = blockIdx.x;
  const int x0 = blockIdx.y*128;
  const int t = threadIdx.x;
  const int w = t >> 6, l = t & 63, lm = l & 15, q = l >> 4;
  const int rr = l >> 2, c8 = (l & 3)*8;
  if (t < 128){
    sm[t]   = mA[(size_t)b*NN + x0 + t];
    sf0[t]  = f0b[b*CC + t];
    scb[t]  = cb[t];
    ssm2[t] = sm2[(size_t)b*NN + x0 + t];
  }
  const u16* Asrc0 = bcT + ((size_t)b*NN + x0)*KK;
  const u16* Asrc1 = bsT + ((size_t)b*NN + x0)*KK;
  const u16* Asrc2 = hT  + ((size_t)b*NN + x0)*CC;
  const u16* Bsrc0 = fcb + (size_t)b*CC*KK;
  const u16* Bsrc1 = fsb + (size_t)b*CC*KK;
  const f32x4 z4 = {0.f,0.f,0.f,0.f};
  f32x4 acc[2][8];
  #pragma unroll
  for (int mt = 0; mt < 2; ++mt)
    #pragma unroll
    for (int nt = 0; nt < 8; ++nt) acc[mt][nt] = z4;

  // prologue: stage s=0 into buf 0
  {
    #pragma unroll
    for (int j = 0; j < 2; ++j){
      const int r = w*32 + j*16 + rr;
      gll16(Asrc0 + (size_t)r*128 + c8, smem + (w*32 + j*16)*32);
      gll16(Bsrc0 + (size_t)r*128 + c8, smem + 4096 + (w*32 + j*16)*32);
    }
  }
  for (int s = 0; s < 12; ++s){
    __syncthreads();                     // buf[s&1] ready
    const int cur = (s & 1)*8192;
    if (s < 11){
      const int s1 = s + 1;
      const int g = s1 >> 2, kk = (s1 & 3)*32;
      const u16* Ap = (g == 0) ? Asrc0 : (g == 1) ? Asrc1 : Asrc2;
      const u16* Bp = (g == 0) ? Bsrc0 : (g == 1) ? Bsrc1 : cwb;
      const int nb = (s1 & 1)*8192;
      #pragma unroll
      for (int j = 0; j < 2; ++j){
        const int r = w*32 + j*16 + rr;
        gll16(Ap + (size_t)r*128 + kk + c8, smem + nb + (w*32 + j*16)*32);
        gll16(Bp + (size_t)r*128 + kk + c8, smem + nb + 4096 + (w*32 + j*16)*32);
      }
    }
    const bf16x8 af0 = *(const bf16x8*)&smem[cur + (w*32      + lm)*32 + q*8];
    const bf16x8 af1 = *(const bf16x8*)&smem[cur + (w*32 + 16 + lm)*32 + q*8];
    #pragma unroll
    for (int nt = 0; nt < 8; ++nt){
      const bf16x8 bf = *(const bf16x8*)&smem[cur + 4096 + (nt*16 + lm)*32 + q*8];
      acc[0][nt] = __builtin_amdgcn_mfma_f32_16x16x32_bf16(af0, bf, acc[0][nt], 0, 0, 0);
      acc[1][nt] = __builtin_amdgcn_mfma_f32_16x16x32_bf16(af1, bf, acc[1][nt], 0, 0, 0);
    }
  }
  __syncthreads();   // staging done; smem becomes result [x][o] stride BPX
  // finish from registers: write hI (8B/lane segments) + x0 partials + LDS [x][o]
  float xpart[8];
  #pragma unroll
  for (int nt = 0; nt < 8; ++nt) xpart[nt] = 0.f;
  #pragma unroll
  for (int mt = 0; mt < 2; ++mt){
    const int xb = w*32 + mt*16 + q*4;
    #pragma unroll
    for (int nt = 0; nt < 8; ++nt){
      const int o = nt*16 + lm;
      const float f0v = sf0[o], cbv = scb[o];
      float v0 = acc[mt][nt][0] + f0v*sm[xb+0] + cbv;
      float v1 = acc[mt][nt][1] + f0v*sm[xb+1] + cbv;
      float v2 = acc[mt][nt][2] + f0v*sm[xb+2] + cbv;
      float v3 = acc[mt][nt][3] + f0v*sm[xb+3] + cbv;
      if (act){ v0 = gelu_f(v0); v1 = gelu_f(v1); v2 = gelu_f(v2); v3 = gelu_f(v3); }
      smem[(xb+0)*BPX + o] = f2bf(v0);
      smem[(xb+1)*BPX + o] = f2bf(v1);
      smem[(xb+2)*BPX + o] = f2bf(v2);
      smem[(xb+3)*BPX + o] = f2bf(v3);
      if (act){
        uint2 st;
        st.x = pk2(v0, v1);
        st.y = pk2(v2, v3);
        *(uint2*)&hI[((size_t)b*CC + o)*NN + x0 + xb] = st;
        xpart[nt] += v0*ssm2[xb+0] + v1*ssm2[xb+1] + v2*ssm2[xb+2] + v3*ssm2[xb+3];
      }
    }
  }
  if (act){
    #pragma unroll
    for (int nt = 0; nt < 8; ++nt){
      float v = xpart[nt];
      v += __shfl_xor(v, 16);
      v += __shfl_xor(v, 32);
      if (q == 0) atomicAdd(&x0next[b*CC + nt*16 + lm], v);
    }
  }
  __syncthreads();
  // hT[x][o] vectorized from [x][o] LDS rows (in-place safe: block owns its x-rows)
  {
    const int x = t >> 1, ohh = (t & 1)*64;
    #pragma unroll 2
    for (int j = 0; j < 8; ++j){
      const uint4 v = *(const uint4*)&smem[x*BPX + ohh + j*8];
      *(uint4*)&hT[((size_t)b*NN + x0 + x)*CC + ohh + j*8] = v;
    }
  }
}

// ---------------------------------------------------------------- final MLP (MFMA)
__global__ __launch_bounds__(256) void final_kernel(
    const u16* __restrict__ hT, const u16* __restrict__ w1T,
    const float* __restrict__ b1, const float* __restrict__ w2, const float* __restrict__ b2,
    float* __restrict__ out)
{
  __shared__ u16 sa[128*APX];
  __shared__ u16 sbt[128*APX];
  __shared__ float sb1[128], sw2[128];
  const int b  = blockIdx.x;
  const int x0 = blockIdx.y*128;
  const int t = threadIdx.x;
  const int w = t >> 6, l = t & 63, lm = l & 15, q = l >> 4;
  if (t < 128){ sb1[t] = b1[t]; sw2[t] = w2[t]; }
  const float b2v = b2[0];
  const f32x4 z4 = {0.f,0.f,0.f,0.f};
  f32x4 acc[2][8];
  #pragma unroll
  for (int mt = 0; mt < 2; ++mt)
    #pragma unroll
    for (int nt = 0; nt < 8; ++nt) acc[mt][nt] = z4;
  const u16* Ap = hT + ((size_t)b*NN + x0)*CC;
  const int row = t >> 2, ch = (t & 3)*8;
  for (int s = 0; s < 4; ++s){
    const int kk = s*32;
    __syncthreads();
    #pragma unroll
    for (int h = 0; h < 2; ++h){
      const int r = row + h*64;
      *(uint4*)&sa [r*APX + ch] = *(const uint4*)&Ap [(size_t)r*CC + kk + ch];
      *(uint4*)&sbt[r*APX + ch] = *(const uint4*)&w1T[(size_t)r*CC + kk + ch];
    }
    __syncthreads();
    bf16x8 af[2];
    af[0] = *(const bf16x8*)&sa[(w*32      + lm)*APX + q*8];
    af[1] = *(const bf16x8*)&sa[(w*32 + 16 + lm)*APX + q*8];
    #pragma unroll
    for (int nt = 0; nt < 8; ++nt){
      const bf16x8 bf = *(const bf16x8*)&sbt[(nt*16 + lm)*APX + q*8];
      acc[0][nt] = __builtin_amdgcn_mfma_f32_16x16x32_bf16(af[0], bf, acc[0][nt], 0, 0, 0);
      acc[1][nt] = __builtin_amdgcn_mfma_f32_16x16x32_bf16(af[1], bf, acc[1][nt], 0, 0, 0);
    }
  }
  #pragma unroll
  for (int mt = 0; mt < 2; ++mt){
    #pragma unroll
    for (int r = 0; r < 4; ++r){
      float s = 0.f;
      #pragma unroll
      for (int nt = 0; nt < 8; ++nt){
        const int f = nt*16 + lm;
        s += gelu_f(acc[mt][nt][r] + sb1[f]) * sw2[f];
      }
      s += __shfl_xor(s, 1);
      s += __shfl_xor(s, 2);
      s += __shfl_xor(s, 4);
      s += __shfl_xor(s, 8);
      if (lm == 0){
        const int x = x0 + w*32 + mt*16 + q*4 + r;
        out[(size_t)b*NN + x] = s + b2v;
      }
    }
  }
}

// ---------------------------------------------------------------- host
extern "C" void kernel_launch(void* const* d_in, const int* in_sizes, int n_in,
                              void* d_out, int out_size, void* d_ws, size_t ws_size,
                              hipStream_t stream)
{
  const float* X     = (const float*)d_in[0];
  const float* modes = (const float*)d_in[1];
  const float* fc0w  = (const float*)d_in[2];
  const float* fc0b  = (const float*)d_in[3];
  const float* wc    = (const float*)d_in[4];
  const float* wsm   = (const float*)d_in[5];
  const float* w0    = (const float*)d_in[6];
  const float* convw = (const float*)d_in[7];
  const float* convb = (const float*)d_in[8];
  const float* fc1w  = (const float*)d_in[9];
  const float* fc1b  = (const float*)d_in[10];
  const float* fc2w  = (const float*)d_in[11];
  const float* fc2b  = (const float*)d_in[12];
  float* out = (float*)d_out;

  const size_t nBKN = (size_t)BB*KK*NN;
  const size_t nBCK = (size_t)BB*CC*KK;
  const size_t nBC  = (size_t)BB*CC;
  const size_t nBN  = (size_t)BB*NN;

  char* p = (char*)d_ws;
  u16* bcs = (u16*)p; p += nBKN*2;
  u16* bss = (u16*)p; p += nBKN*2;
  u16* bcT = (u16*)p; p += nBKN*2;
  u16* bsT = (u16*)p; p += nBKN*2;
  u16* hI  = (u16*)p; p += nBKN*2;
  u16* hT  = (u16*)p; p += nBKN*2;
  float* xcA = (float*)p; p += nBCK*4;
  float* xsA = (float*)p; p += nBCK*4;
  float* x0A = (float*)p; p += 4*nBC*4;    // 4 per-layer slots
  u16* fcb = (u16*)p; p += nBCK*2;
  u16* fsb = (u16*)p; p += nBCK*2;
  float* f0b = (float*)p; p += nBC*4;
  float* mA  = (float*)p; p += nBN*4;
  float* sm2 = (float*)p; p += nBN*4;
  u16* cwb = (u16*)p; p += (size_t)LL*CC*CC*2;
  u16* w1T = (u16*)p; p += (size_t)CC*CC*2;

  hipMemsetAsync(x0A, 0, 4*nBC*sizeof(float), stream);
  cvt_kernel<<<1, 256, 0, stream>>>(convw, fc1w, cwb, w1T);
  bases_kernel<<<dim3(BB, NN/64), 256, 0, stream>>>(X, modes, bcs, bss, bcT, bsT, mA, sm2);
  fc0_kernel<<<dim3(BB, NN/128), 256, 0, stream>>>(X, fc0w, fc0b, sm2, hT, hI, x0A);

  for (int l = 0; l < LL; ++l){
    hipMemsetAsync(xcA, 0, 2*nBCK*sizeof(float), stream);   // xc | xs contiguous
    proj_kernel<<<dim3(BB, 16), 256, 0, stream>>>(hI, bcs, bss, xcA, xsA);
    mix_kernel<<<dim3(BB, 32), 256, 0, stream>>>(xcA, xsA,
        wc + (size_t)l*CC*CC*KK, wsm + (size_t)l*CC*CC*KK, fcb, fsb);
    f0_kernel<<<dim3(BB), 128, 0, stream>>>(x0A + (size_t)l*nBC, w0 + (size_t)l*CC*CC, f0b);
    fused_kernel<<<dim3(BB, NN/128), 256, 0, stream>>>(
        bcT, bsT, hT, fcb, fsb,
        cwb + (size_t)l*CC*CC, convb + (size_t)l*CC,
        f0b, mA, sm2, hI,
        x0A + (size_t)(l+1 < LL ? l+1 : 0)*nBC,   // unused when act==0
        (l < LL-1) ? 1 : 0);
  }
  final_kernel<<<dim3(BB, NN/128), 256, 0, stream>>>(hT, w1T, fc1b, fc2w, fc2b, out);
}